// Round 9
// baseline (12711.962 us; speedup 1.0000x reference)
//
#include <hip/hip_runtime.h>

typedef unsigned int u32;
typedef unsigned short u16;
typedef unsigned long long u64;

#define DEV static __device__ __forceinline__

DEV float sigf(float x){ return 1.0f / (1.0f + expf(-x)); }

DEV u64  ldA64(const u64* p){ return __hip_atomic_load(p, __ATOMIC_RELAXED, __HIP_MEMORY_SCOPE_AGENT); }
DEV void stA64(u64* p, u64 v){ __hip_atomic_store(p, v, __ATOMIC_RELAXED, __HIP_MEMORY_SCOPE_AGENT); }
DEV float ldAf(const float* p){ return __hip_atomic_load(p, __ATOMIC_RELAXED, __HIP_MEMORY_SCOPE_AGENT); }
DEV void stAf(float* p, float v){ __hip_atomic_store(p, v, __ATOMIC_RELAXED, __HIP_MEMORY_SCOPE_AGENT); }
DEV u32  ldA32(const u32* p){ return __hip_atomic_load(p, __ATOMIC_RELAXED, __HIP_MEMORY_SCOPE_AGENT); }

// tagged h exchange: hi32 = f32 bits, lo32 = step tag
DEV u64 packHV(float h, u32 tag){ return (((u64)__float_as_uint(h)) << 32) | (u64)tag; }
DEV float unpackH(u64 v){ return __uint_as_float((u32)(v >> 32)); }

// tagged key: [mapped f32 (32b)][0x1FFFF - row (17b)][tag (15b)]
DEV u64 packKeyT(float v, u32 row, u32 tagv){
  u32 u = __float_as_uint(v);
  u = (u & 0x80000000u) ? ~u : (u | 0x80000000u);
  return (((u64)u) << 32) | ((u64)(0x1FFFFu - row) << 15) | (u64)tagv;
}

#if defined(__has_builtin)
#if __has_builtin(__builtin_amdgcn_sdot4)
#define HAVE_SDOT4 1
#endif
#endif
DEV int dot4i8(u32 a, u32 b, int acc){
#ifdef HAVE_SDOT4
  return __builtin_amdgcn_sdot4((int)a, (int)b, acc, false);
#else
  int s = acc;
  s += ((int)(a << 24) >> 24) * ((int)(b << 24) >> 24);
  s += ((int)(a << 16) >> 24) * ((int)(b << 16) >> 24);
  s += ((int)(a <<  8) >> 24) * ((int)(b <<  8) >> 24);
  s += ((int)(a      ) >> 24) * ((int)(b      ) >> 24);
  return s;
#endif
}

DEV int q8c(float v){ int q = (int)rintf(v); return q < -127 ? -127 : (q > 127 ? 127 : q); }
DEV u32 pk4(int a, int b, int c, int d){
  return (u32)(a & 255) | ((u32)(b & 255) << 8) | ((u32)(c & 255) << 16) | ((u32)(d & 255) << 24);
}

DEV float dotrow(const float4 A, const float4 B, const float4 Cc, const float4 D,
                 const float4 q0, const float4 q1, const float4 q2, const float4 q3){
  float s;
  s  = A.x*q0.x + A.y*q0.y + A.z*q0.z + A.w*q0.w;
  s += B.x*q1.x + B.y*q1.y + B.z*q1.z + B.w*q1.w;
  s += Cc.x*q2.x + Cc.y*q2.y + Cc.z*q2.z + Cc.w*q2.w;
  s += D.x*q3.x + D.y*q3.y + D.z*q3.z + D.w*q3.w;
  return s;
}

// ---------------- LDS ----------------
struct SM {
  float w1s[24576];    // 96 KB decoder layer-1 weights (thread-SoA)
  float inpP[1600];
  float linp[1024];
  u32   qhp[256];
  float srow[200];
  float erow[200];
  float red[12];       // [0..3] max|h|, [4..7] sum|qh|, [8..11] lb
  float dots[16];
  float cst0[4];
  float cst1[4];
  u64   wkey[4];
};

template<int CPT> DEV int pidx(int c){ int b = c / CPT; return b * (CPT + 4) + (c - b * CPT); }

template<int CPT, int DIN>
DEV void loadw(float* wreg, const float* Wih, const float* Whh, int jb4){
  const int tid = threadIdx.x, r = tid >> 4, p = tid & 15;
  const int R = 512 * (r >> 2) + jb4 + (r & 3);
  const float* s1 = Wih + (size_t)R * DIN;
  const float* s2 = Whh + (size_t)R * 512;
  #pragma unroll
  for (int k = 0; k < CPT; k += 4){
    const int col = p * CPT + k;
    const float4 v = *(const float4*)((col < DIN) ? (s1 + col) : (s2 + col - DIN));
    wreg[k] = v.x; wreg[k+1] = v.y; wreg[k+2] = v.z; wreg[k+3] = v.w;
  }
}

// split dot: LOW=true accumulates cols < DIN (a k-prefix per thread), LOW=false the suffix.
template<int CPT, int DIN, bool LOW>
DEV float dotp_reg(const float* wreg, const float* inpP, float acc){
  const int p = threadIdx.x & 15;
  const float* xi = inpP + p * (CPT + 4);
  #pragma unroll
  for (int k = 0; k < CPT; k += 4){
    const int col = p * CPT + k;
    if ((col < DIN) == LOW){
      const float4 xv = *(const float4*)(xi + k);
      acc = fmaf(wreg[k],   xv.x, acc);
      acc = fmaf(wreg[k+1], xv.y, acc);
      acc = fmaf(wreg[k+2], xv.z, acc);
      acc = fmaf(wreg[k+3], xv.w, acc);
    }
  }
  return acc;
}
DEV void dred16(float acc, float* dots){
  #pragma unroll
  for (int s = 1; s < 16; s <<= 1) acc += __shfl_xor(acc, s, 64);
  if ((threadIdx.x & 15) == 0) dots[threadIdx.x >> 4] = acc;
}

template<int CPT>
DEV void dot16(const float* wreg, const float* inpP, float* dots){
  const int tid = threadIdx.x, p = tid & 15;
  const float* xi = inpP + p * (CPT + 4);
  float acc = 0.f;
  #pragma unroll
  for (int k = 0; k < CPT; k += 4){
    const float4 xv = *(const float4*)(xi + k);
    acc = fmaf(wreg[k],   xv.x, acc);
    acc = fmaf(wreg[k+1], xv.y, acc);
    acc = fmaf(wreg[k+2], xv.z, acc);
    acc = fmaf(wreg[k+3], xv.w, acc);
  }
  dred16(acc, dots);
}

DEV void dot16_w1(const float* w1s, const float* inpP, float* dots){
  const int tid = threadIdx.x, p = tid & 15;
  const float* xi = inpP + p * 100;
  float acc = 0.f;
  #pragma unroll
  for (int k = 0; k < 96; k += 4){
    const float4 w4 = *(const float4*)(w1s + (k >> 2) * 1024 + tid * 4);
    const float4 xv = *(const float4*)(xi + k);
    acc = fmaf(w4.x, xv.x, acc);
    acc = fmaf(w4.y, xv.y, acc);
    acc = fmaf(w4.z, xv.z, acc);
    acc = fmaf(w4.w, xv.w, acc);
  }
  dred16(acc, dots);
}

// ---------------- phase barrier (encoder transitions only) ----------------
DEV void gbar_phase(u32* g, u32 ev){
  __syncthreads();
  if (threadIdx.x == 0){
    __hip_atomic_fetch_add(g, 1u, __ATOMIC_RELEASE, __HIP_MEMORY_SCOPE_AGENT);
    const u32 tgt = 256u * ev;
    while (ldA32(g) < tgt) __builtin_amdgcn_s_sleep(8);
    (void)__hip_atomic_fetch_add(g, 0u, __ATOMIC_ACQUIRE, __HIP_MEMORY_SCOPE_AGENT);
    asm volatile("" ::: "memory");
  }
  __syncthreads();
}

// ---------------- distributed tagged-key exchange ----------------
DEV u64 exchange(u64* slots, u64 kwave, int w, u32 tagv, SM& sm){
  const int tid = threadIdx.x;
  if ((tid & 63) == 0) sm.wkey[tid >> 6] = kwave;
  __syncthreads();
  if (tid == 0){
    u64 k4 = sm.wkey[0];
    if (sm.wkey[1] > k4) k4 = sm.wkey[1];
    if (sm.wkey[2] > k4) k4 = sm.wkey[2];
    if (sm.wkey[3] > k4) k4 = sm.wkey[3];
    stA64(slots + (size_t)w * 16, k4);
  }
  __syncthreads();
  const u64* p = slots + (size_t)tid * 16;
  u64 kv = ldA64(p);
  while ((u32)(kv & 0x7FFFu) != tagv){ __builtin_amdgcn_s_sleep(1); kv = ldA64(p); }
  #pragma unroll
  for (int s = 1; s < 64; s <<= 1){
    const u64 o = (u64)__shfl_xor((unsigned long long)kv, s, 64);
    if (o > kv) kv = o;
  }
  if ((tid & 63) == 0) sm.wkey[tid >> 6] = kv;
  __syncthreads();
  u64 gk = sm.wkey[0];
  if (sm.wkey[1] > gk) gk = sm.wkey[1];
  if (sm.wkey[2] > gk) gk = sm.wkey[2];
  if (sm.wkey[3] > gk) gk = sm.wkey[3];
  return gk;
}

// ---------------- encoder layer (split-dot: x-prefix under the h-wait) ----------------
template<int DIN, bool WRITE_XS>
DEV void enc_layer(const float* __restrict__ xg, float* __restrict__ xs_out,
                   const float* __restrict__ Wih, const float* __restrict__ Whh,
                   const float* __restrict__ bias,
                   u64* __restrict__ ht, float* __restrict__ hfinL, float* __restrict__ cfinL,
                   const int dir, const int jb4, SM& sm)
{
  constexpr int CPT = (DIN + 512) / 16;
  constexpr int NX  = DIN / 256;
  const int tid = threadIdx.x;
  float wreg[CPT];
  loadw<CPT, DIN>(wreg, Wih + (size_t)dir * 2048 * DIN, Whh + (size_t)dir * 2048 * 512, jb4);
  float b_i = 0.f, b_f = 0.f, b_g = 0.f, b_o = 0.f;
  if (tid < 4){
    const int j = jb4 + tid;
    sm.cst0[tid] = 0.f;
    b_i = bias[dir*2048 +        j];
    b_f = bias[dir*2048 +  512 + j];
    b_g = bias[dir*2048 + 1024 + j];
    b_o = bias[dir*2048 + 1536 + j];
  }
  float xr[NX];
  {
    const int t0 = dir ? 1023 : 0;
    #pragma unroll
    for (int i = 0; i < NX; ++i){
      const int c = tid + 256 * i;
      xr[i] = (DIN == 512) ? xg[(size_t)t0 * DIN + c] : ldAf(xg + (size_t)t0 * DIN + c);
    }
  }
  for (int step = 0; step < 1024; ++step){
    #pragma unroll
    for (int i = 0; i < NX; ++i) sm.inpP[pidx<CPT>(tid + 256 * i)] = xr[i];
    __syncthreads();                                  // S1: x staged
    const u64* hp = ht + (step & 1) * 512;
    const u32 want = (u32)step;
    u64 a = ldA64(hp + tid*2);
    u64 b = ldA64(hp + tid*2 + 1);
    float acc = dotp_reg<CPT, DIN, true>(wreg, sm.inpP, 0.f);   // x-part under h-wait
    while ((u32)a != want){ __builtin_amdgcn_s_sleep(1); a = ldA64(hp + tid*2); }
    while ((u32)b != want){ __builtin_amdgcn_s_sleep(1); b = ldA64(hp + tid*2 + 1); }
    sm.inpP[pidx<CPT>(DIN + tid*2)]     = unpackH(a);
    sm.inpP[pidx<CPT>(DIN + tid*2 + 1)] = unpackH(b);
    __syncthreads();                                  // S2: h staged
    if (step < 1023){
      const int tn = dir ? (1022 - step) : (step + 1);
      #pragma unroll
      for (int i = 0; i < NX; ++i){
        const int c = tid + 256 * i;
        xr[i] = (DIN == 512) ? xg[(size_t)tn * DIN + c] : ldAf(xg + (size_t)tn * DIN + c);
      }
    }
    acc = dotp_reg<CPT, DIN, false>(wreg, sm.inpP, acc);
    dred16(acc, sm.dots);
    __syncthreads();                                  // S3: dots ready
    if (tid < 4){
      const float gi = sm.dots[tid]      + b_i;
      const float gf = sm.dots[4 + tid]  + b_f;
      const float gg = sm.dots[8 + tid]  + b_g;
      const float go = sm.dots[12 + tid] + b_o;
      const float cc = sigf(gf) * sm.cst0[tid] + sigf(gi) * tanhf(gg);
      const float hh = sigf(go) * tanhf(cc);
      sm.cst0[tid] = cc;
      const int t = dir ? (1023 - step) : step;
      const int j = jb4 + tid;
      stA64(ht + ((step + 1) & 1) * 512 + j, packHV(hh, (u32)(step + 1)));
      if (WRITE_XS) stAf(xs_out + (size_t)t * 1024 + dir * 512 + j, hh);
      if (step == 1023){ stAf(hfinL + dir*512 + j, hh); stAf(cfinL + dir*512 + j, cc); }
    }
  }
}

// ---------------- init ----------------
__global__ void bilstm_init(u32* ws){
  for (u32 i = threadIdx.x; i < 49152u; i += 256u) ws[i] = 0u;
}

// ---------------- lin_W f32 -> int8 (per-row scale) + meta {sw, sum|q|} ----------------
__global__ void cvt_q8(const float* __restrict__ w, uint4* __restrict__ q8,
                       float* __restrict__ meta, const int C){
  const int wv = threadIdx.x >> 6, lane = threadIdx.x & 63;
  const int stride = gridDim.x * 4;
  for (int r = blockIdx.x * 4 + wv; r < C; r += stride){
    const float4* src = (const float4*)(w + (size_t)r * 1024) + lane * 4;
    const float4 v0 = src[0], v1 = src[1], v2 = src[2], v3 = src[3];
    float m = fmaxf(fmaxf(fmaxf(fabsf(v0.x), fabsf(v0.y)), fmaxf(fabsf(v0.z), fabsf(v0.w))),
                    fmaxf(fmaxf(fabsf(v1.x), fabsf(v1.y)), fmaxf(fabsf(v1.z), fabsf(v1.w))));
    m = fmaxf(m, fmaxf(fmaxf(fabsf(v2.x), fabsf(v2.y)), fmaxf(fabsf(v2.z), fabsf(v2.w))));
    m = fmaxf(m, fmaxf(fmaxf(fabsf(v3.x), fabsf(v3.y)), fmaxf(fabsf(v3.z), fabsf(v3.w))));
    #pragma unroll
    for (int s = 1; s < 64; s <<= 1) m = fmaxf(m, __shfl_xor(m, s, 64));
    const float inv = (m > 1e-30f) ? (127.0f / m) : 0.0f;
    const float sw = m * (1.0f / 127.0f);
    const int qa0 = q8c(v0.x*inv), qa1 = q8c(v0.y*inv), qa2 = q8c(v0.z*inv), qa3 = q8c(v0.w*inv);
    const int qb0 = q8c(v1.x*inv), qb1 = q8c(v1.y*inv), qb2 = q8c(v1.z*inv), qb3 = q8c(v1.w*inv);
    const int qc0 = q8c(v2.x*inv), qc1 = q8c(v2.y*inv), qc2 = q8c(v2.z*inv), qc3 = q8c(v2.w*inv);
    const int qd0 = q8c(v3.x*inv), qd1 = q8c(v3.y*inv), qd2 = q8c(v3.z*inv), qd3 = q8c(v3.w*inv);
    uint4 st;
    st.x = pk4(qa0,qa1,qa2,qa3); st.y = pk4(qb0,qb1,qb2,qb3);
    st.z = pk4(qc0,qc1,qc2,qc3); st.w = pk4(qd0,qd1,qd2,qd3);
    q8[(size_t)r * 64 + lane] = st;
    float sq = (float)(abs(qa0)+abs(qa1)+abs(qa2)+abs(qa3)+abs(qb0)+abs(qb1)+abs(qb2)+abs(qb3)
                     + abs(qc0)+abs(qc1)+abs(qc2)+abs(qc3)+abs(qd0)+abs(qd1)+abs(qd2)+abs(qd3));
    #pragma unroll
    for (int s = 1; s < 64; s <<= 1) sq += __shfl_xor(sq, s, 64);
    if (lane == 0){ meta[2*r] = sw; meta[2*r+1] = sq; }
  }
}

// ---------------- persistent kernel ----------------
template<int LINQ8>
__global__ __launch_bounds__(256, 1)
void bilstm_persist(const float* __restrict__ x,
                    const float* __restrict__ eW0, const float* __restrict__ eU0, const float* __restrict__ eb0,
                    const float* __restrict__ eW1, const float* __restrict__ eU1, const float* __restrict__ eb1,
                    const float* __restrict__ dW0, const float* __restrict__ dU0, const float* __restrict__ db0,
                    const float* __restrict__ dW1, const float* __restrict__ dU1, const float* __restrict__ db1,
                    const float* __restrict__ linW, const float* __restrict__ linb,
                    const float* __restrict__ emb, const float* __restrict__ bos,
                    float* __restrict__ out, float* __restrict__ ws, const int L, const int C)
{
  __shared__ SM sm;
  const int w = blockIdx.x;
  const int tid = threadIdx.x;
  const int dir = (w >> 2) & 1;
  const int jb4 = ((w >> 3) * 4 + (w & 3)) * 4;

  u64*  htagE = (u64*)ws;
  u64*  h0t   = htagE + 4096;
  u64*  h1t   = h0t + 2048;
  float* hfin = (float*)(h1t + 2048);
  float* cfin = hfin + 2048;
  u32*  gbar  = (u32*)(cfin + 2048);
  u64*  gkeyB = (u64*)((char*)ws + 163840);
  const float* meta = (const float*)((const char*)ws + 196608);
  const uint4* q8u  = (const uint4*)((const char*)ws + 602112);
  float* xs1  = out;

  // ================= encoder =================
  enc_layer<512,  true >(x,   xs1,     eW0, eU0, eb0, htagE + (0*2 + dir)*1024, hfin,        cfin,        dir, jb4, sm);
  gbar_phase(gbar, 1);
  enc_layer<1024, false>(xs1, nullptr, eW1, eU1, eb1, htagE + (1*2 + dir)*1024, hfin + 1024, cfin + 1024, dir, jb4, sm);
  gbar_phase(gbar, 2);

  // ================= decoder =================
  float w0reg[64];
  loadw<64, 512>(w0reg, dW0 + (size_t)dir*2048*512, dU0 + (size_t)dir*2048*512, jb4);
  { // stage layer-1 weights into LDS SoA
    const int r = tid >> 4, p = tid & 15;
    const int R = 512 * (r >> 2) + jb4 + (r & 3);
    const float* s1 = dW1 + (size_t)dir*2048*1024 + (size_t)R * 1024;
    const float* s2 = dU1 + (size_t)dir*2048*512  + (size_t)R * 512;
    #pragma unroll
    for (int k = 0; k < 96; k += 4){
      const int col = p * 96 + k;
      const float4 v = *(const float4*)((col < 1024) ? (s1 + col) : (s2 + col - 1024));
      *(float4*)(sm.w1s + (k >> 2) * 1024 + tid * 4) = v;
    }
  }

  float b0i=0,b0f=0,b0g=0,b0o=0, b1i=0,b1f=0,b1g=0,b1o=0;
  if (tid < 4){
    const int j = jb4 + tid;
    sm.cst0[tid] = ldAf(&cfin[dir*512 + j]);
    sm.cst1[tid] = ldAf(&cfin[1024 + dir*512 + j]);
    b0i = db0[dir*2048 + j];        b0f = db0[dir*2048 + 512 + j];
    b0g = db0[dir*2048 + 1024 + j]; b0o = db0[dir*2048 + 1536 + j];
    b1i = db1[dir*2048 + j];        b1f = db1[dir*2048 + 512 + j];
    b1g = db1[dir*2048 + 1024 + j]; b1o = db1[dir*2048 + 1536 + j];
  }
  const int rbase = w * 196 + (w < 81 ? w : 81);
  const int rn    = 196 + (w < 81 ? 1 : 0);
  int tok = 0;

  for (int t = 0; t < L; ++t){
    const u32 tag = (u32)(t + 1);
    // ---- layer 0 ----
    {
      const float* src = (t == 0) ? bos : (emb + (size_t)tok * 512);
      sm.inpP[pidx<64>(tid)]       = src[tid];
      sm.inpP[pidx<64>(tid + 256)] = src[tid + 256];
      if (t == 0){
        sm.inpP[pidx<64>(512 + tid*2)]     = ldAf(&hfin[dir*512 + tid*2]);
        sm.inpP[pidx<64>(512 + tid*2 + 1)] = ldAf(&hfin[dir*512 + tid*2 + 1]);
      } else {
        const u64* hp = h0t + (dir*2 + ((t-1) & 1)) * 512;
        const u32 want = (u32)t;
        u64 a = ldA64(hp + tid*2), b = ldA64(hp + tid*2 + 1);
        while ((u32)a != want){ __builtin_amdgcn_s_sleep(1); a = ldA64(hp + tid*2); }
        while ((u32)b != want){ __builtin_amdgcn_s_sleep(1); b = ldA64(hp + tid*2 + 1); }
        sm.inpP[pidx<64>(512 + tid*2)]     = unpackH(a);
        sm.inpP[pidx<64>(512 + tid*2 + 1)] = unpackH(b);
      }
      __syncthreads();
      dot16<64>(w0reg, sm.inpP, sm.dots);
      __syncthreads();
      if (tid < 4){
        const float gi = sm.dots[tid] + b0i, gf = sm.dots[4+tid] + b0f;
        const float gg = sm.dots[8+tid] + b0g, go = sm.dots[12+tid] + b0o;
        const float cc = sigf(gf) * sm.cst0[tid] + sigf(gi) * tanhf(gg);
        const float hh = sigf(go) * tanhf(cc);
        sm.cst0[tid] = cc;
        stA64(h0t + (dir*2 + (t & 1))*512 + jb4 + tid, packHV(hh, tag));
      }
      __syncthreads();
    }

    // ---- layer 1 ----
    {
      #pragma unroll
      for (int i = 0; i < 4; ++i){
        const int c = tid + 256 * i;
        const int d = c >> 9, idx = c & 511;
        const u64* hp = h0t + (d*2 + (t & 1)) * 512 + idx;
        u64 v = ldA64(hp);
        while ((u32)v != tag){ __builtin_amdgcn_s_sleep(1); v = ldA64(hp); }
        sm.inpP[pidx<96>(c)] = unpackH(v);
      }
      if (t == 0){
        sm.inpP[pidx<96>(1024 + tid*2)]     = ldAf(&hfin[1024 + dir*512 + tid*2]);
        sm.inpP[pidx<96>(1024 + tid*2 + 1)] = ldAf(&hfin[1024 + dir*512 + tid*2 + 1]);
      } else {
        const u64* hq = h1t + (dir*2 + ((t-1) & 1)) * 512;
        const u32 want1 = (u32)t;
        u64 e = ldA64(hq + tid*2), f = ldA64(hq + tid*2 + 1);
        while ((u32)e != want1){ __builtin_amdgcn_s_sleep(1); e = ldA64(hq + tid*2); }
        while ((u32)f != want1){ __builtin_amdgcn_s_sleep(1); f = ldA64(hq + tid*2 + 1); }
        sm.inpP[pidx<96>(1024 + tid*2)]     = unpackH(e);
        sm.inpP[pidx<96>(1024 + tid*2 + 1)] = unpackH(f);
      }
      __syncthreads();
      dot16_w1(sm.w1s, sm.inpP, sm.dots);
      __syncthreads();
      if (tid < 4){
        const float gi = sm.dots[tid] + b1i, gf = sm.dots[4+tid] + b1f;
        const float gg = sm.dots[8+tid] + b1g, go = sm.dots[12+tid] + b1o;
        const float cc = sigf(gf) * sm.cst1[tid] + sigf(gi) * tanhf(gg);
        const float hh = sigf(go) * tanhf(cc);
        sm.cst1[tid] = cc;
        stA64(h1t + (dir*2 + (t & 1))*512 + jb4 + tid, packHV(hh, tag));
      }
    }

    // ---- linear + argmax ----
    const int wv = tid >> 6, lane = tid & 63;
    {
      float pm = 0.f;
      #pragma unroll
      for (int i = 0; i < 4; ++i){
        const int c = tid + 256 * i;
        const int d = c >> 9, idx = c & 511;
        const u64* hp = h1t + (d*2 + (t & 1)) * 512 + idx;
        u64 v = ldA64(hp);
        while ((u32)v != tag){ __builtin_amdgcn_s_sleep(1); v = ldA64(hp); }
        const float hv = unpackH(v);
        sm.linp[c] = hv;
        pm = fmaxf(pm, fabsf(hv));
      }

      if constexpr (LINQ8){
        #pragma unroll
        for (int s = 1; s < 64; s <<= 1) pm = fmaxf(pm, __shfl_xor(pm, s, 64));
        if (lane == 0) sm.red[wv] = pm;
        __syncthreads();
        const float maxh = fmaxf(fmaxf(sm.red[0], sm.red[1]), fmaxf(sm.red[2], sm.red[3]));
        const float inv_sh = (maxh > 1e-30f) ? (127.0f / maxh) : 0.0f;
        const float shs = maxh * (1.0f / 127.0f);
        {
          const float4 hv = *(const float4*)(sm.linp + 4 * tid);
          const int q0 = q8c(hv.x * inv_sh), q1 = q8c(hv.y * inv_sh);
          const int q2 = q8c(hv.z * inv_sh), q3 = q8c(hv.w * inv_sh);
          sm.qhp[tid] = pk4(q0, q1, q2, q3);
          float sq = (float)(abs(q0) + abs(q1) + abs(q2) + abs(q3));
          #pragma unroll
          for (int s = 1; s < 64; s <<= 1) sq += __shfl_xor(sq, s, 64);
          if (lane == 0) sm.red[4 + wv] = sq;
        }
        __syncthreads();
        const float Sqh = sm.red[4] + sm.red[5] + sm.red[6] + sm.red[7];
        const u32 qh0 = sm.qhp[lane*4], qh1 = sm.qhp[lane*4+1];
        const u32 qh2 = sm.qhp[lane*4+2], qh3 = sm.qhp[lane*4+3];
        float lb = -3.0e38f;
        // 16 rows per wave per iteration: deep ILP so L2/L3 latency overlaps
        for (int i0 = wv; i0 < rn; i0 += 64){
          int idx[16];
          uint4 wq[16];
          #pragma unroll
          for (int j = 0; j < 16; ++j){
            int i = i0 + 4 * j; if (i > rn - 1) i = rn - 1;
            idx[j] = i;
            wq[j] = q8u[(size_t)(rbase + i) * 64 + lane];
          }
          int d[16];
          #pragma unroll
          for (int j = 0; j < 16; ++j)
            d[j] = dot4i8(wq[j].x, qh0, dot4i8(wq[j].y, qh1, dot4i8(wq[j].z, qh2, dot4i8(wq[j].w, qh3, 0))));
          #pragma unroll
          for (int s = 1; s < 64; s <<= 1){
            #pragma unroll
            for (int j = 0; j < 16; ++j) d[j] += __shfl_xor(d[j], s, 64);
          }
          if (lane == 0){
            #pragma unroll
            for (int j = 0; j < 16; ++j){
              const int i = idx[j], row = rbase + i;
              const float2 M = *(const float2*)(meta + 2 * row);
              const float csc = M.x * shs;
              const float sv = csc * (float)d[j] + linb[row];
              const float ev = csc * (0.5f * (M.y + Sqh) + 256.0f) * 1.0002f + 1e-4f;
              out[(size_t)t * C + row] = sv;
              sm.srow[i] = sv; sm.erow[i] = ev;
              lb = fmaxf(lb, sv - ev);
            }
          }
        }
        if (lane == 0) sm.red[8 + wv] = lb;
        __syncthreads();
        const float Lb = fmaxf(fmaxf(sm.red[8], sm.red[9]), fmaxf(sm.red[10], sm.red[11]));
        // exact f32 recheck of candidates (provably includes this WG's true argmax)
        u64 kwB = packKeyT(-3.0e38f, 0x1FFFFu, tag);
        const float4* ip4 = (const float4*)(sm.linp + lane * 16);
        const float4 q0f = ip4[0], q1f = ip4[1], q2f = ip4[2], q3f = ip4[3];
        for (int i = wv; i < rn; i += 4){
          if (sm.srow[i] + sm.erow[i] >= Lb){
            const int row = rbase + i;
            const float4* wp = (const float4*)(linW + (size_t)row * 1024) + lane * 4;
            float s = dotrow(wp[0], wp[1], wp[2], wp[3], q0f, q1f, q2f, q3f);
            #pragma unroll
            for (int sh2 = 1; sh2 < 64; sh2 <<= 1) s += __shfl_xor(s, sh2, 64);
            if (lane == 0){
              s += linb[row];
              const u64 k = packKeyT(s, (u32)row, tag);
              if (k > kwB) kwB = k;
            }
          }
        }
        const u64 gkB = exchange(gkeyB, kwB, w, tag, sm);
        tok = (int)(0x1FFFFu - ((u32)(gkB >> 15) & 0x1FFFFu));
        if (w == 0 && tid == 0) out[(size_t)L * C + t] = (float)tok;
      } else {
        __syncthreads();
        const float4* ip4 = (const float4*)(sm.linp + lane * 16);
        const float4 q0 = ip4[0], q1 = ip4[1], q2 = ip4[2], q3 = ip4[3];
        u64 kmax = packKeyT(-3.0e38f, 0x1FFFFu, tag);
        const int rmaxr = rbase + rn - 1;
        for (int i0 = wv; i0 < rn; i0 += 16){
          const int ra = rbase + i0;
          const int rb = (ra + 4  > rmaxr) ? rmaxr : ra + 4;
          const int rc = (ra + 8  > rmaxr) ? rmaxr : ra + 8;
          const int rd = (ra + 12 > rmaxr) ? rmaxr : ra + 12;
          const float ba = linb[ra], bb = linb[rb], bc = linb[rc], bd = linb[rd];
          const float4* pa = (const float4*)(linW + (size_t)ra * 1024) + lane * 4;
          const float4* pb = (const float4*)(linW + (size_t)rb * 1024) + lane * 4;
          const float4* pc = (const float4*)(linW + (size_t)rc * 1024) + lane * 4;
          const float4* pd = (const float4*)(linW + (size_t)rd * 1024) + lane * 4;
          float sa = dotrow(pa[0],pa[1],pa[2],pa[3], q0,q1,q2,q3);
          float sb = dotrow(pb[0],pb[1],pb[2],pb[3], q0,q1,q2,q3);
          float sc = dotrow(pc[0],pc[1],pc[2],pc[3], q0,q1,q2,q3);
          float sd = dotrow(pd[0],pd[1],pd[2],pd[3], q0,q1,q2,q3);
          #pragma unroll
          for (int sh = 1; sh < 64; sh <<= 1){
            sa += __shfl_xor(sa, sh, 64);
            sb += __shfl_xor(sb, sh, 64);
            sc += __shfl_xor(sc, sh, 64);
            sd += __shfl_xor(sd, sh, 64);
          }
          if (lane == 0){
            sa += ba; sb += bb; sc += bc; sd += bd;
            out[(size_t)t * C + ra] = sa;
            out[(size_t)t * C + rb] = sb;
            out[(size_t)t * C + rc] = sc;
            out[(size_t)t * C + rd] = sd;
            u64 k;
            k = packKeyT(sa, (u32)ra, tag); if (k > kmax) kmax = k;
            k = packKeyT(sb, (u32)rb, tag); if (k > kmax) kmax = k;
            k = packKeyT(sc, (u32)rc, tag); if (k > kmax) kmax = k;
            k = packKeyT(sd, (u32)rd, tag); if (k > kmax) kmax = k;
          }
        }
        const u64 gkB = exchange(gkeyB, kmax, w, tag, sm);
        tok = (int)(0x1FFFFu - ((u32)(gkB >> 15) & 0x1FFFFu));
        if (w == 0 && tid == 0) out[(size_t)L * C + t] = (float)tok;
      }
    }
  }
}

// ---------------- launch ----------------
extern "C" void kernel_launch(void* const* d_in, const int* in_sizes, int n_in,
                              void* d_out, int out_size, void* d_ws, size_t ws_size,
                              hipStream_t stream)
{
  const float* x    = (const float*)d_in[0];
  const float* eW0  = (const float*)d_in[1];
  const float* eU0  = (const float*)d_in[2];
  const float* eb0  = (const float*)d_in[3];
  const float* eW1  = (const float*)d_in[4];
  const float* eU1  = (const float*)d_in[5];
  const float* eb1  = (const float*)d_in[6];
  const float* dW0  = (const float*)d_in[7];
  const float* dU0  = (const float*)d_in[8];
  const float* db0  = (const float*)d_in[9];
  const float* dW1  = (const float*)d_in[10];
  const float* dU1  = (const float*)d_in[11];
  const float* db1  = (const float*)d_in[12];
  const float* linW = (const float*)d_in[13];
  const float* linb = (const float*)d_in[14];
  const float* emb  = (const float*)d_in[15];
  const float* bos  = (const float*)d_in[16];

  const int C = in_sizes[14];            // 50257
  const int L = out_size / (C + 1);      // 150

  const size_t need = 602112 + (size_t)C * 1024;
  const bool q8 = (ws_size >= need);

  hipLaunchKernelGGL(bilstm_init, dim3(1), dim3(256), 0, stream, (u32*)d_ws);
  if (q8){
    hipLaunchKernelGGL(cvt_q8, dim3(2048), dim3(256), 0, stream,
                       linW, (uint4*)((char*)d_ws + 602112),
                       (float*)((char*)d_ws + 196608), C);
    hipLaunchKernelGGL((bilstm_persist<1>), dim3(256), dim3(256), 0, stream,
                       x, eW0, eU0, eb0, eW1, eU1, eb1,
                       dW0, dU0, db0, dW1, dU1, db1,
                       linW, linb, emb, bos,
                       (float*)d_out, (float*)d_ws, L, C);
  } else {
    hipLaunchKernelGGL((bilstm_persist<0>), dim3(256), dim3(256), 0, stream,
                       x, eW0, eU0, eb0, eW1, eU1, eb1,
                       dW0, dU0, db0, dW1, dU1, db1,
                       linW, linb, emb, bos,
                       (float*)d_out, (float*)d_ws, L, C);
  }
}

// Round 10
// 10709.609 us; speedup vs baseline: 1.1870x; 1.1870x over previous
//
#include <hip/hip_runtime.h>
#include <hip/hip_fp16.h>

typedef unsigned int u32;
typedef unsigned short u16;
typedef unsigned long long u64;

#define DEV static __device__ __forceinline__

DEV float sigf(float x){ return 1.0f / (1.0f + expf(-x)); }

DEV u64  ldA64(const u64* p){ return __hip_atomic_load(p, __ATOMIC_RELAXED, __HIP_MEMORY_SCOPE_AGENT); }
DEV void stA64(u64* p, u64 v){ __hip_atomic_store(p, v, __ATOMIC_RELAXED, __HIP_MEMORY_SCOPE_AGENT); }
DEV float ldAf(const float* p){ return __hip_atomic_load(p, __ATOMIC_RELAXED, __HIP_MEMORY_SCOPE_AGENT); }
DEV void stAf(float* p, float v){ __hip_atomic_store(p, v, __ATOMIC_RELAXED, __HIP_MEMORY_SCOPE_AGENT); }
DEV u32  ldA32(const u32* p){ return __hip_atomic_load(p, __ATOMIC_RELAXED, __HIP_MEMORY_SCOPE_AGENT); }

// tagged h exchange: hi32 = f32 bits, lo32 = step tag
DEV u64 packHV(float h, u32 tag){ return (((u64)__float_as_uint(h)) << 32) | (u64)tag; }
DEV float unpackH(u64 v){ return __uint_as_float((u32)(v >> 32)); }

// tagged key: [mapped f32 (32b)][0x1FFFF - row (17b)][tag (15b)]
DEV u64 packKeyT(float v, u32 row, u32 tagv){
  u32 u = __float_as_uint(v);
  u = (u & 0x80000000u) ? ~u : (u | 0x80000000u);
  return (((u64)u) << 32) | ((u64)(0x1FFFFu - row) << 15) | (u64)tagv;
}

// fp16 row fragment (8 halves in a uint4) dotted with 8 f32 inputs (f32 math)
DEV float dot8h(const uint4 A, const float4 a, const float4 b){
  const __half2* h = (const __half2*)&A;
  const float2 f0 = __half22float2(h[0]);
  const float2 f1 = __half22float2(h[1]);
  const float2 f2 = __half22float2(h[2]);
  const float2 f3 = __half22float2(h[3]);
  float s;
  s  = f0.x*a.x + f0.y*a.y + f1.x*a.z + f1.y*a.w;
  s += f2.x*b.x + f2.y*b.y + f3.x*b.z + f3.y*b.w;
  return s;
}

DEV float dotrow(const float4 A, const float4 B, const float4 Cc, const float4 D,
                 const float4 q0, const float4 q1, const float4 q2, const float4 q3){
  float s;
  s  = A.x*q0.x + A.y*q0.y + A.z*q0.z + A.w*q0.w;
  s += B.x*q1.x + B.y*q1.y + B.z*q1.z + B.w*q1.w;
  s += Cc.x*q2.x + Cc.y*q2.y + Cc.z*q2.z + Cc.w*q2.w;
  s += D.x*q3.x + D.y*q3.y + D.z*q3.z + D.w*q3.w;
  return s;
}

// ---------------- LDS ----------------
struct SM {
  float w1s[24576];    // 96 KB decoder layer-1 weights (thread-SoA)
  float inpP[1600];
  float linp[1024];    // h1(t) raw; doubles as h1 cache for L1(t+1)
  float h0c[1024];     // h0(t) raw cache (filled during L1's poll)
  float srow[200];
  float erow[200];
  float red[8];
  float dots[16];
  float cst0[4];
  float cst1[4];
  u64   wkey[4];
};

template<int CPT> DEV int pidx(int c){ int b = c / CPT; return b * (CPT + 4) + (c - b * CPT); }

// decoder row map: r = gate*4 + jj (R7 layout)
template<int CPT, int DIN>
DEV void loadw(float* wreg, const float* Wih, const float* Whh, int jb4){
  const int tid = threadIdx.x, r = tid >> 4, p = tid & 15;
  const int R = 512 * (r >> 2) + jb4 + (r & 3);
  const float* s1 = Wih + (size_t)R * DIN;
  const float* s2 = Whh + (size_t)R * 512;
  #pragma unroll
  for (int k = 0; k < CPT; k += 4){
    const int col = p * CPT + k;
    const float4 v = *(const float4*)((col < DIN) ? (s1 + col) : (s2 + col - DIN));
    wreg[k] = v.x; wreg[k+1] = v.y; wreg[k+2] = v.z; wreg[k+3] = v.w;
  }
}

// encoder row map: rows r = 4*jj + gate so output jj's gates live in wave jj
template<int CPT, int DIN>
DEV void loadw_enc(float* wreg, const float* Wih, const float* Whh, int jb4){
  const int tid = threadIdx.x, r = tid >> 4, p = tid & 15;
  const int R = 512 * (r & 3) + jb4 + (r >> 2);
  const float* s1 = Wih + (size_t)R * DIN;
  const float* s2 = Whh + (size_t)R * 512;
  #pragma unroll
  for (int k = 0; k < CPT; k += 4){
    const int col = p * CPT + k;
    const float4 v = *(const float4*)((col < DIN) ? (s1 + col) : (s2 + col - DIN));
    wreg[k] = v.x; wreg[k+1] = v.y; wreg[k+2] = v.z; wreg[k+3] = v.w;
  }
}

// split dot: LOW=true accumulates cols < DIN, LOW=false the suffix (bit-exact chained)
template<int CPT, int DIN, bool LOW>
DEV float dotp_reg(const float* wreg, const float* inpP, float acc){
  const int p = threadIdx.x & 15;
  const float* xi = inpP + p * (CPT + 4);
  #pragma unroll
  for (int k = 0; k < CPT; k += 4){
    const int col = p * CPT + k;
    if ((col < DIN) == LOW){
      const float4 xv = *(const float4*)(xi + k);
      acc = fmaf(wreg[k],   xv.x, acc);
      acc = fmaf(wreg[k+1], xv.y, acc);
      acc = fmaf(wreg[k+2], xv.z, acc);
      acc = fmaf(wreg[k+3], xv.w, acc);
    }
  }
  return acc;
}

DEV void dred16(float acc, float* dots){
  #pragma unroll
  for (int s = 1; s < 16; s <<= 1) acc += __shfl_xor(acc, s, 64);
  if ((threadIdx.x & 15) == 0) dots[threadIdx.x >> 4] = acc;
}

// full 64-col slice dot (CPT=64): identical per-thread chain to dot16<64>
DEV float dot64_slice(const float* wreg, const float* inpP){
  const int p = threadIdx.x & 15;
  const float* xi = inpP + p * 68;
  float acc = 0.f;
  #pragma unroll
  for (int k = 0; k < 64; k += 4){
    const float4 xv = *(const float4*)(xi + k);
    acc = fmaf(wreg[k],   xv.x, acc);
    acc = fmaf(wreg[k+1], xv.y, acc);
    acc = fmaf(wreg[k+2], xv.z, acc);
    acc = fmaf(wreg[k+3], xv.w, acc);
  }
  return acc;
}

DEV void dot16_w1(const float* w1s, const float* inpP, float* dots){
  const int tid = threadIdx.x, p = tid & 15;
  const float* xi = inpP + p * 100;
  float acc = 0.f;
  #pragma unroll
  for (int k = 0; k < 96; k += 4){
    const float4 w4 = *(const float4*)(w1s + (k >> 2) * 1024 + tid * 4);
    const float4 xv = *(const float4*)(xi + k);
    acc = fmaf(w4.x, xv.x, acc);
    acc = fmaf(w4.y, xv.y, acc);
    acc = fmaf(w4.z, xv.z, acc);
    acc = fmaf(w4.w, xv.w, acc);
  }
  dred16(acc, dots);
}

// ---------------- phase barrier (encoder transitions only) ----------------
DEV void gbar_phase(u32* g, u32 ev){
  __syncthreads();
  if (threadIdx.x == 0){
    __hip_atomic_fetch_add(g, 1u, __ATOMIC_RELEASE, __HIP_MEMORY_SCOPE_AGENT);
    const u32 tgt = 256u * ev;
    while (ldA32(g) < tgt) __builtin_amdgcn_s_sleep(8);
    (void)__hip_atomic_fetch_add(g, 0u, __ATOMIC_ACQUIRE, __HIP_MEMORY_SCOPE_AGENT);
    asm volatile("" ::: "memory");
  }
  __syncthreads();
}

// ---------------- encoder layer (split-dot + in-wave gates; 2 syncs/step) ----------------
template<int DIN, bool WRITE_XS>
DEV void enc_layer(const float* __restrict__ xg, float* __restrict__ xs_out,
                   const float* __restrict__ Wih, const float* __restrict__ Whh,
                   const float* __restrict__ bias,
                   u64* __restrict__ ht, float* __restrict__ hfinL, float* __restrict__ cfinL,
                   const int dir, const int jb4, SM& sm)
{
  constexpr int CPT = (DIN + 512) / 16;
  constexpr int NX  = DIN / 256;
  const int tid = threadIdx.x;
  const int wj  = tid >> 6;                        // wave id = output index jj
  float wreg[CPT];
  loadw_enc<CPT, DIN>(wreg, Wih + (size_t)dir * 2048 * DIN, Whh + (size_t)dir * 2048 * 512, jb4);
  const int j = jb4 + wj;
  const float b_i = bias[dir*2048 +        j];
  const float b_f = bias[dir*2048 +  512 + j];
  const float b_g = bias[dir*2048 + 1024 + j];
  const float b_o = bias[dir*2048 + 1536 + j];
  float creg = 0.f;
  float xr[NX];
  {
    const int t0 = dir ? 1023 : 0;
    #pragma unroll
    for (int i = 0; i < NX; ++i){
      const int c = tid + 256 * i;
      xr[i] = (DIN == 512) ? xg[(size_t)t0 * DIN + c] : ldAf(xg + (size_t)t0 * DIN + c);
    }
  }
  for (int step = 0; step < 1024; ++step){
    #pragma unroll
    for (int i = 0; i < NX; ++i) sm.inpP[pidx<CPT>(tid + 256 * i)] = xr[i];
    __syncthreads();                                  // S1: x staged
    const u64* hp = ht + (step & 1) * 512;
    const u32 want = (u32)step;
    u64 a = ldA64(hp + tid*2);
    u64 b = ldA64(hp + tid*2 + 1);
    float acc = dotp_reg<CPT, DIN, true>(wreg, sm.inpP, 0.f);   // x-part under h-wait
    while ((u32)a != want){ __builtin_amdgcn_s_sleep(1); a = ldA64(hp + tid*2); }
    while ((u32)b != want){ __builtin_amdgcn_s_sleep(1); b = ldA64(hp + tid*2 + 1); }
    sm.inpP[pidx<CPT>(DIN + tid*2)]     = unpackH(a);
    sm.inpP[pidx<CPT>(DIN + tid*2 + 1)] = unpackH(b);
    __syncthreads();                                  // S2: h staged
    if (step < 1023){
      const int tn = dir ? (1022 - step) : (step + 1);
      #pragma unroll
      for (int i = 0; i < NX; ++i){
        const int c = tid + 256 * i;
        xr[i] = (DIN == 512) ? xg[(size_t)tn * DIN + c] : ldAf(xg + (size_t)tn * DIN + c);
      }
    }
    acc = dotp_reg<CPT, DIN, false>(wreg, sm.inpP, acc);
    #pragma unroll
    for (int s = 1; s < 16; s <<= 1) acc += __shfl_xor(acc, s, 64);
    // wave wj holds gates of output jj=wj in lane-groups 0/16/32/48
    const float gi = __shfl(acc,  0, 64) + b_i;
    const float gf = __shfl(acc, 16, 64) + b_f;
    const float gg = __shfl(acc, 32, 64) + b_g;
    const float go = __shfl(acc, 48, 64) + b_o;
    const float cc = sigf(gf) * creg + sigf(gi) * tanhf(gg);
    const float hh = sigf(go) * tanhf(cc);
    creg = cc;
    if ((tid & 63) == 0){
      const int t = dir ? (1023 - step) : step;
      stA64(ht + ((step + 1) & 1) * 512 + j, packHV(hh, (u32)(step + 1)));
      if (WRITE_XS) stAf(xs_out + (size_t)t * 1024 + dir * 512 + j, hh);
      if (step == 1023){ stAf(hfinL + dir*512 + j, hh); stAf(cfinL + dir*512 + j, cc); }
    }
  }
}

// ---------------- init ----------------
__global__ void bilstm_init(u32* ws){
  for (u32 i = threadIdx.x; i < 32768u; i += 256u) ws[i] = 0u;
}

// ---------------- lin_W f32 -> fp16 + per-row max|w| ----------------
__global__ void cvt_lin(const float* __restrict__ w, uint4* __restrict__ o,
                        float* __restrict__ maxw, const int C){
  const int wv = threadIdx.x >> 6, lane = threadIdx.x & 63;
  const int stride = gridDim.x * 4;
  for (int r = blockIdx.x * 4 + wv; r < C; r += stride){
    const float4* src = (const float4*)(w + (size_t)r * 1024) + lane * 4;
    const float4 v0 = src[0], v1 = src[1], v2 = src[2], v3 = src[3];
    uint4 p0, p1;
    __half2 h;
    h = __floats2half2_rn(v0.x, v0.y); p0.x = *(const u32*)&h;
    h = __floats2half2_rn(v0.z, v0.w); p0.y = *(const u32*)&h;
    h = __floats2half2_rn(v1.x, v1.y); p0.z = *(const u32*)&h;
    h = __floats2half2_rn(v1.z, v1.w); p0.w = *(const u32*)&h;
    h = __floats2half2_rn(v2.x, v2.y); p1.x = *(const u32*)&h;
    h = __floats2half2_rn(v2.z, v2.w); p1.y = *(const u32*)&h;
    h = __floats2half2_rn(v3.x, v3.y); p1.z = *(const u32*)&h;
    h = __floats2half2_rn(v3.z, v3.w); p1.w = *(const u32*)&h;
    uint4* dst = o + (size_t)r * 128 + lane * 2;
    dst[0] = p0; dst[1] = p1;
    float m = fmaxf(fmaxf(fmaxf(fabsf(v0.x), fabsf(v0.y)), fmaxf(fabsf(v0.z), fabsf(v0.w))),
                    fmaxf(fmaxf(fabsf(v1.x), fabsf(v1.y)), fmaxf(fabsf(v1.z), fabsf(v1.w))));
    m = fmaxf(m, fmaxf(fmaxf(fabsf(v2.x), fabsf(v2.y)), fmaxf(fabsf(v2.z), fabsf(v2.w))));
    m = fmaxf(m, fmaxf(fmaxf(fabsf(v3.x), fabsf(v3.y)), fmaxf(fabsf(v3.z), fabsf(v3.w))));
    #pragma unroll
    for (int s = 1; s < 64; s <<= 1) m = fmaxf(m, __shfl_xor(m, s, 64));
    if (lane == 0) maxw[r] = m;
  }
}

// ---------------- persistent kernel ----------------
template<int LINFP16>
__global__ __launch_bounds__(256, 1)
void bilstm_persist(const float* __restrict__ x,
                    const float* __restrict__ eW0, const float* __restrict__ eU0, const float* __restrict__ eb0,
                    const float* __restrict__ eW1, const float* __restrict__ eU1, const float* __restrict__ eb1,
                    const float* __restrict__ dW0, const float* __restrict__ dU0, const float* __restrict__ db0,
                    const float* __restrict__ dW1, const float* __restrict__ dU1, const float* __restrict__ db1,
                    const float* __restrict__ linW, const float* __restrict__ linb,
                    const float* __restrict__ emb, const float* __restrict__ bos,
                    float* __restrict__ out, float* __restrict__ ws, const int L, const int C)
{
  __shared__ SM sm;
  const int w = blockIdx.x;
  const int tid = threadIdx.x;
  const int dir = (w >> 2) & 1;                    // dir confined to 4 XCDs
  const int jb4 = ((w >> 3) * 4 + (w & 3)) * 4;

  u64*  htagE = (u64*)ws;                          // [0,32768)
  u64*  h0t   = htagE + 4096;                      // [32768,49152)
  u64*  h1t   = h0t + 2048;                        // [49152,65536)
  float* hfin = (float*)(h1t + 2048);              // [65536,73728)
  float* cfin = hfin + 2048;                       // [73728,81920)
  u32*  gbar  = (u32*)(cfin + 2048);               // [81920,81924)
  u64*  gkey  = (u64*)((char*)ws + 98304);         // [98304,131072): 256 x 128B slots
  const u16*  linH = (const u16*)((const char*)ws + 131072);
  const float* maxw = (const float*)((const char*)ws + 131072 + (size_t)C * 2048);
  float* xs1  = out;                               // scratch; decoder rewrites all of out

  // ================= encoder =================
  enc_layer<512,  true >(x,   xs1,     eW0, eU0, eb0, htagE + (0*2 + dir)*1024, hfin,        cfin,        dir, jb4, sm);
  gbar_phase(gbar, 1);
  enc_layer<1024, false>(xs1, nullptr, eW1, eU1, eb1, htagE + (1*2 + dir)*1024, hfin + 1024, cfin + 1024, dir, jb4, sm);
  gbar_phase(gbar, 2);

  // ================= decoder =================
  float w0reg[64];
  loadw<64, 512>(w0reg, dW0 + (size_t)dir*2048*512, dU0 + (size_t)dir*2048*512, jb4);
  { // stage layer-1 weights into LDS SoA
    const int r = tid >> 4, p = tid & 15;
    const int R = 512 * (r >> 2) + jb4 + (r & 3);
    const float* s1 = dW1 + (size_t)dir*2048*1024 + (size_t)R * 1024;
    const float* s2 = dU1 + (size_t)dir*2048*512  + (size_t)R * 512;
    #pragma unroll
    for (int k = 0; k < 96; k += 4){
      const int col = p * 96 + k;
      const float4 v = *(const float4*)((col < 1024) ? (s1 + col) : (s2 + col - 1024));
      *(float4*)(sm.w1s + (k >> 2) * 1024 + tid * 4) = v;
    }
  }

  float b0i=0,b0f=0,b0g=0,b0o=0, b1i=0,b1f=0,b1g=0,b1o=0;
  if (tid < 4){
    const int j = jb4 + tid;
    sm.cst0[tid] = ldAf(&cfin[dir*512 + j]);
    sm.cst1[tid] = ldAf(&cfin[1024 + dir*512 + j]);
    b0i = db0[dir*2048 + j];        b0f = db0[dir*2048 + 512 + j];
    b0g = db0[dir*2048 + 1024 + j]; b0o = db0[dir*2048 + 1536 + j];
    b1i = db1[dir*2048 + j];        b1f = db1[dir*2048 + 512 + j];
    b1g = db1[dir*2048 + 1024 + j]; b1o = db1[dir*2048 + 1536 + j];
  }
  const int rbase = w * 196 + (w < 81 ? w : 81);
  const int rn    = 196 + (w < 81 ? 1 : 0);
  int tok = 0;
  float accPre = 0.f;

  for (int t = 0; t < L; ++t){
    const u32 tag = (u32)(t + 1);
    // ---- layer 0 (no global poll: h-half staged from cache / hfin) ----
    {
      if (t == 0){
        sm.inpP[pidx<64>(tid)]       = bos[tid];
        sm.inpP[pidx<64>(tid + 256)] = bos[tid + 256];
        sm.inpP[pidx<64>(512 + tid*2)]     = ldAf(&hfin[dir*512 + tid*2]);
        sm.inpP[pidx<64>(512 + tid*2 + 1)] = ldAf(&hfin[dir*512 + tid*2 + 1]);
      } else {
        const float* src = emb + (size_t)tok * 512;
        sm.inpP[pidx<64>(tid)]       = src[tid];
        sm.inpP[pidx<64>(tid + 256)] = src[tid + 256];
        // h-half already staged + p>=8 dots precomputed during exchange wait
      }
      __syncthreads();
      float acc;
      if (t == 0) acc = dot64_slice(w0reg, sm.inpP);
      else        acc = ((tid & 15) >= 8) ? accPre : dot64_slice(w0reg, sm.inpP);
      dred16(acc, sm.dots);
      __syncthreads();
      if (tid < 4){
        const float gi = sm.dots[tid] + b0i, gf = sm.dots[4+tid] + b0f;
        const float gg = sm.dots[8+tid] + b0g, go = sm.dots[12+tid] + b0o;
        const float cc = sigf(gf) * sm.cst0[tid] + sigf(gi) * tanhf(gg);
        const float hh = sigf(go) * tanhf(cc);
        sm.cst0[tid] = cc;
        stA64(h0t + (dir*2 + (t & 1))*512 + jb4 + tid, packHV(hh, tag));
      }
      __syncthreads();
    }

    // ---- layer 1 (polls h0(t); h1(t-1) from linp cache) ----
    {
      #pragma unroll
      for (int i = 0; i < 4; ++i){
        const int c = tid + 256 * i;
        const int d = c >> 9, idx = c & 511;
        const u64* hp = h0t + (d*2 + (t & 1)) * 512 + idx;
        u64 v = ldA64(hp);
        while ((u32)v != tag){ __builtin_amdgcn_s_sleep(1); v = ldA64(hp); }
        const float hv = unpackH(v);
        sm.inpP[pidx<96>(c)] = hv;
        sm.h0c[c] = hv;                              // cache for L0(t+1)
      }
      if (t == 0){
        sm.inpP[pidx<96>(1024 + tid*2)]     = ldAf(&hfin[1024 + dir*512 + tid*2]);
        sm.inpP[pidx<96>(1024 + tid*2 + 1)] = ldAf(&hfin[1024 + dir*512 + tid*2 + 1]);
      } else {
        sm.inpP[pidx<96>(1024 + tid*2)]     = sm.linp[dir*512 + tid*2];
        sm.inpP[pidx<96>(1024 + tid*2 + 1)] = sm.linp[dir*512 + tid*2 + 1];
      }
      __syncthreads();
      dot16_w1(sm.w1s, sm.inpP, sm.dots);
      __syncthreads();
      if (tid < 4){
        const float gi = sm.dots[tid] + b1i, gf = sm.dots[4+tid] + b1f;
        const float gg = sm.dots[8+tid] + b1g, go = sm.dots[12+tid] + b1o;
        const float cc = sigf(gf) * sm.cst1[tid] + sigf(gi) * tanhf(gg);
        const float hh = sigf(go) * tanhf(cc);
        sm.cst1[tid] = cc;
        stA64(h1t + (dir*2 + (t & 1))*512 + jb4 + tid, packHV(hh, tag));
      }
    }

    // ---- linear + argmax ----
    const int wv = tid >> 6, lane = tid & 63;
    u64 kloc;
    {
      float pabs = 0.f;
      #pragma unroll
      for (int i = 0; i < 4; ++i){
        const int c = tid + 256 * i;
        const int d = c >> 9, idx = c & 511;
        const u64* hp = h1t + (d*2 + (t & 1)) * 512 + idx;
        u64 v = ldA64(hp);
        while ((u32)v != tag){ __builtin_amdgcn_s_sleep(1); v = ldA64(hp); }
        const float hv = unpackH(v);
        sm.linp[c] = hv;                             // doubles as h1 cache for L1(t+1)
        pabs += fabsf(hv);
      }
      if constexpr (LINFP16){
        #pragma unroll
        for (int s = 1; s < 64; s <<= 1) pabs += __shfl_xor(pabs, s, 64);
        if (lane == 0) sm.red[wv] = pabs;
      }
      __syncthreads();

      const float4* ip4 = (const float4*)(sm.linp + lane * 16);
      const float4 q0 = ip4[0], q1 = ip4[1], q2 = ip4[2], q3 = ip4[3];
      u64 kmax = packKeyT(-3.0e38f, 0x1FFFFu, tag);
      const int rmaxr = rbase + rn - 1;

      if constexpr (LINFP16){
        const float sumabs = sm.red[0] + sm.red[1] + sm.red[2] + sm.red[3];
        const float cErr = sumabs * 7.5e-4f;
        float lb = -3.0e38f;
        for (int i0 = wv; i0 < rn; i0 += 16){
          const int ia = i0;
          const int ib = (i0 + 4  > rn - 1) ? rn - 1 : i0 + 4;
          const int ic = (i0 + 8  > rn - 1) ? rn - 1 : i0 + 8;
          const int id = (i0 + 12 > rn - 1) ? rn - 1 : i0 + 12;
          const int ra = rbase + ia, rb = rbase + ib, rc = rbase + ic, rd = rbase + id;
          const uint4* pa = (const uint4*)(linH + (size_t)ra * 1024) + lane * 2;
          const uint4* pb = (const uint4*)(linH + (size_t)rb * 1024) + lane * 2;
          const uint4* pc = (const uint4*)(linH + (size_t)rc * 1024) + lane * 2;
          const uint4* pd = (const uint4*)(linH + (size_t)rd * 1024) + lane * 2;
          const uint4 A0 = pa[0], A1 = pa[1];
          const uint4 B0 = pb[0], B1 = pb[1];
          const uint4 C0 = pc[0], C1 = pc[1];
          const uint4 D0 = pd[0], D1 = pd[1];
          float sa = dot8h(A0, q0, q1) + dot8h(A1, q2, q3);
          float sb = dot8h(B0, q0, q1) + dot8h(B1, q2, q3);
          float sc = dot8h(C0, q0, q1) + dot8h(C1, q2, q3);
          float sd = dot8h(D0, q0, q1) + dot8h(D1, q2, q3);
          #pragma unroll
          for (int sh = 1; sh < 64; sh <<= 1){
            sa += __shfl_xor(sa, sh, 64);
            sb += __shfl_xor(sb, sh, 64);
            sc += __shfl_xor(sc, sh, 64);
            sd += __shfl_xor(sd, sh, 64);
          }
          if (lane == 0){
            sa += linb[ra]; sb += linb[rb]; sc += linb[rc]; sd += linb[rd];
            out[(size_t)t * C + ra] = sa;
            out[(size_t)t * C + rb] = sb;
            out[(size_t)t * C + rc] = sc;
            out[(size_t)t * C + rd] = sd;
            const float ea = maxw[ra] * cErr + 1e-4f;
            const float eb = maxw[rb] * cErr + 1e-4f;
            const float ec = maxw[rc] * cErr + 1e-4f;
            const float ed = maxw[rd] * cErr + 1e-4f;
            sm.srow[ia] = sa; sm.erow[ia] = ea;
            sm.srow[ib] = sb; sm.erow[ib] = eb;
            sm.srow[ic] = sc; sm.erow[ic] = ec;
            sm.srow[id] = sd; sm.erow[id] = ed;
            lb = fmaxf(lb, sa - ea); lb = fmaxf(lb, sb - eb);
            lb = fmaxf(lb, sc - ec); lb = fmaxf(lb, sd - ed);
          }
        }
        if (lane == 0) sm.red[4 + wv] = lb;
        __syncthreads();
        const float Lb = fmaxf(fmaxf(sm.red[4], sm.red[5]), fmaxf(sm.red[6], sm.red[7]));
        // exact f32 recheck of candidates (provably includes this WG's true argmax)
        for (int i = wv; i < rn; i += 4){
          if (sm.srow[i] + sm.erow[i] >= Lb){
            const int row = rbase + i;
            const float4* wp = (const float4*)(linW + (size_t)row * 1024) + lane * 4;
            float s = dotrow(wp[0], wp[1], wp[2], wp[3], q0, q1, q2, q3);
            #pragma unroll
            for (int sh2 = 1; sh2 < 64; sh2 <<= 1) s += __shfl_xor(s, sh2, 64);
            if (lane == 0){
              s += linb[row];
              const u64 k = packKeyT(s, (u32)row, tag);
              if (k > kmax) kmax = k;
            }
          }
        }
      } else {
        for (int i0 = wv; i0 < rn; i0 += 16){
          const int ra = rbase + i0;
          const int rb = (ra + 4  > rmaxr) ? rmaxr : ra + 4;
          const int rc = (ra + 8  > rmaxr) ? rmaxr : ra + 8;
          const int rd = (ra + 12 > rmaxr) ? rmaxr : ra + 12;
          const float ba = linb[ra], bb = linb[rb], bc = linb[rc], bd = linb[rd];
          const float4* pa = (const float4*)(linW + (size_t)ra * 1024) + lane * 4;
          const float4* pb = (const float4*)(linW + (size_t)rb * 1024) + lane * 4;
          const float4* pc = (const float4*)(linW + (size_t)rc * 1024) + lane * 4;
          const float4* pd = (const float4*)(linW + (size_t)rd * 1024) + lane * 4;
          float sa = dotrow(pa[0],pa[1],pa[2],pa[3], q0,q1,q2,q3);
          float sb = dotrow(pb[0],pb[1],pb[2],pb[3], q0,q1,q2,q3);
          float sc = dotrow(pc[0],pc[1],pc[2],pc[3], q0,q1,q2,q3);
          float sd = dotrow(pd[0],pd[1],pd[2],pd[3], q0,q1,q2,q3);
          #pragma unroll
          for (int sh = 1; sh < 64; sh <<= 1){
            sa += __shfl_xor(sa, sh, 64);
            sb += __shfl_xor(sb, sh, 64);
            sc += __shfl_xor(sc, sh, 64);
            sd += __shfl_xor(sd, sh, 64);
          }
          if (lane == 0){
            sa += ba; sb += bb; sc += bc; sd += bd;
            out[(size_t)t * C + ra] = sa;
            out[(size_t)t * C + rb] = sb;
            out[(size_t)t * C + rc] = sc;
            out[(size_t)t * C + rd] = sd;
            u64 k;
            k = packKeyT(sa, (u32)ra, tag); if (k > kmax) kmax = k;
            k = packKeyT(sb, (u32)rb, tag); if (k > kmax) kmax = k;
            k = packKeyT(sc, (u32)rc, tag); if (k > kmax) kmax = k;
            k = packKeyT(sd, (u32)rd, tag); if (k > kmax) kmax = k;
          }
        }
      }
      kloc = kmax;
    }

    // ---- key store + L0(t+1) pre-work + exchange poll ----
    if (lane == 0) sm.wkey[wv] = kloc;
    __syncthreads();
    if (tid == 0){
      u64 k4 = sm.wkey[0];
      if (sm.wkey[1] > k4) k4 = sm.wkey[1];
      if (sm.wkey[2] > k4) k4 = sm.wkey[2];
      if (sm.wkey[3] > k4) k4 = sm.wkey[3];
      stA64(gkey + (size_t)w * 16, k4);              // own 128-B slot
    }
    if (t + 1 < L){                                  // stage L0(t+1) h-half from cache
      sm.inpP[pidx<64>(512 + tid*2)]     = sm.h0c[dir*512 + tid*2];
      sm.inpP[pidx<64>(512 + tid*2 + 1)] = sm.h0c[dir*512 + tid*2 + 1];
    }
    __syncthreads();
    if (t + 1 < L && (tid & 15) >= 8)
      accPre = dot64_slice(w0reg, sm.inpP);          // p>=8 slices are pure h-region
    {
      const u64* p = gkey + (size_t)tid * 16;
      u64 kv = ldA64(p);
      while ((u32)(kv & 0x7FFFu) != tag){ __builtin_amdgcn_s_sleep(1); kv = ldA64(p); }
      #pragma unroll
      for (int s = 1; s < 64; s <<= 1){
        const u64 o = (u64)__shfl_xor((unsigned long long)kv, s, 64);
        if (o > kv) kv = o;
      }
      if ((tid & 63) == 0) sm.wkey[tid >> 6] = kv;
    }
    __syncthreads();
    {
      u64 gk = sm.wkey[0];
      if (sm.wkey[1] > gk) gk = sm.wkey[1];
      if (sm.wkey[2] > gk) gk = sm.wkey[2];
      if (sm.wkey[3] > gk) gk = sm.wkey[3];
      tok = (int)(0x1FFFFu - ((u32)(gk >> 15) & 0x1FFFFu));
      if (w == 0 && tid == 0) out[(size_t)L * C + t] = (float)tok;
    }
  }
}

// ---------------- launch ----------------
extern "C" void kernel_launch(void* const* d_in, const int* in_sizes, int n_in,
                              void* d_out, int out_size, void* d_ws, size_t ws_size,
                              hipStream_t stream)
{
  const float* x    = (const float*)d_in[0];
  const float* eW0  = (const float*)d_in[1];
  const float* eU0  = (const float*)d_in[2];
  const float* eb0  = (const float*)d_in[3];
  const float* eW1  = (const float*)d_in[4];
  const float* eU1  = (const float*)d_in[5];
  const float* eb1  = (const float*)d_in[6];
  const float* dW0  = (const float*)d_in[7];
  const float* dU0  = (const float*)d_in[8];
  const float* db0  = (const float*)d_in[9];
  const float* dW1  = (const float*)d_in[10];
  const float* dU1  = (const float*)d_in[11];
  const float* db1  = (const float*)d_in[12];
  const float* linW = (const float*)d_in[13];
  const float* linb = (const float*)d_in[14];
  const float* emb  = (const float*)d_in[15];
  const float* bos  = (const float*)d_in[16];

  const int C = in_sizes[14];            // 50257
  const int L = out_size / (C + 1);      // 150
  const int nlin = in_sizes[13];         // C*1024

  const size_t need = 131072 + (size_t)nlin * 2 + (size_t)C * 4;
  const bool fp16lin = (ws_size >= need);

  hipLaunchKernelGGL(bilstm_init, dim3(1), dim3(256), 0, stream, (u32*)d_ws);
  if (fp16lin){
    hipLaunchKernelGGL(cvt_lin, dim3(2048), dim3(256), 0, stream,
                       linW, (uint4*)((char*)d_ws + 131072),
                       (float*)((char*)d_ws + 131072 + (size_t)C * 2048), C);
    hipLaunchKernelGGL((bilstm_persist<1>), dim3(256), dim3(256), 0, stream,
                       x, eW0, eU0, eb0, eW1, eU1, eb1,
                       dW0, dU0, db0, dW1, dU1, db1,
                       linW, linb, emb, bos,
                       (float*)d_out, (float*)d_ws, L, C);
  } else {
    hipLaunchKernelGGL((bilstm_persist<0>), dim3(256), dim3(256), 0, stream,
                       x, eW0, eU0, eb0, eW1, eU1, eb1,
                       dW0, dU0, db0, dW1, dU1, db1,
                       linW, linb, emb, bos,
                       (float*)d_out, (float*)d_ws, L, C);
  }
}

// Round 11
// 8814.688 us; speedup vs baseline: 1.4421x; 1.2150x over previous
//
#include <hip/hip_runtime.h>
#include <hip/hip_fp16.h>

typedef unsigned int u32;
typedef unsigned short u16;
typedef unsigned long long u64;

#define DEV static __device__ __forceinline__

DEV float sigf(float x){ return 1.0f / (1.0f + expf(-x)); }

DEV u64  ldA64(const u64* p){ return __hip_atomic_load(p, __ATOMIC_RELAXED, __HIP_MEMORY_SCOPE_AGENT); }
DEV void stA64(u64* p, u64 v){ __hip_atomic_store(p, v, __ATOMIC_RELAXED, __HIP_MEMORY_SCOPE_AGENT); }
DEV float ldAf(const float* p){ return __hip_atomic_load(p, __ATOMIC_RELAXED, __HIP_MEMORY_SCOPE_AGENT); }
DEV void stAf(float* p, float v){ __hip_atomic_store(p, v, __ATOMIC_RELAXED, __HIP_MEMORY_SCOPE_AGENT); }
DEV u32  ldA32(const u32* p){ return __hip_atomic_load(p, __ATOMIC_RELAXED, __HIP_MEMORY_SCOPE_AGENT); }

// tagged h exchange: hi32 = f32 bits, lo32 = step tag
DEV u64 packHV(float h, u32 tag){ return (((u64)__float_as_uint(h)) << 32) | (u64)tag; }
DEV float unpackH(u64 v){ return __uint_as_float((u32)(v >> 32)); }

// tagged argmax key: [mapped f32 (32b)][0x1FFFF - row (17b)][tag (15b)]
DEV u64 packKeyT(float v, u32 row, u32 tagv){
  u32 u = __float_as_uint(v);
  u = (u & 0x80000000u) ? ~u : (u | 0x80000000u);
  return (((u64)u) << 32) | ((u64)(0x1FFFFu - row) << 15) | (u64)tagv;
}

// fp16 row fragment (8 halves in a uint4) dotted with 8 f32 inputs (f32 math)
DEV float dot8h(const uint4 A, const float4 a, const float4 b){
  const __half2* h = (const __half2*)&A;
  const float2 f0 = __half22float2(h[0]);
  const float2 f1 = __half22float2(h[1]);
  const float2 f2 = __half22float2(h[2]);
  const float2 f3 = __half22float2(h[3]);
  float s;
  s  = f0.x*a.x + f0.y*a.y + f1.x*a.z + f1.y*a.w;
  s += f2.x*b.x + f2.y*b.y + f3.x*b.z + f3.y*b.w;
  return s;
}

DEV float dotrow(const float4 A, const float4 B, const float4 Cc, const float4 D,
                 const float4 q0, const float4 q1, const float4 q2, const float4 q3){
  float s;
  s  = A.x*q0.x + A.y*q0.y + A.z*q0.z + A.w*q0.w;
  s += B.x*q1.x + B.y*q1.y + B.z*q1.z + B.w*q1.w;
  s += Cc.x*q2.x + Cc.y*q2.y + Cc.z*q2.z + Cc.w*q2.w;
  s += D.x*q3.x + D.y*q3.y + D.z*q3.z + D.w*q3.w;
  return s;
}

// ---------------- LDS ----------------
struct SM {
  float w1s[24576];    // 96 KB decoder layer-1 weights (thread-SoA)
  float inpP[1600];
  float linp[1024];    // h1(t) raw; doubles as h1 cache for L1(t+1)
  float h0c[1024];     // h0(t) raw cache (filled during L1's poll) for L0(t+1)
  float srow[200];
  float erow[200];
  float red[8];
  float dots[16];
  float cst0[4];
  float cst1[4];
  u64   wkey[4];
};

template<int CPT> DEV int pidx(int c){ int b = c / CPT; return b * (CPT + 4) + (c - b * CPT); }

template<int CPT, int DIN>
DEV void loadw(float* wreg, const float* Wih, const float* Whh, int jb4){
  const int tid = threadIdx.x, r = tid >> 4, p = tid & 15;
  const int R = 512 * (r >> 2) + jb4 + (r & 3);
  const float* s1 = Wih + (size_t)R * DIN;
  const float* s2 = Whh + (size_t)R * 512;
  #pragma unroll
  for (int k = 0; k < CPT; k += 4){
    const int col = p * CPT + k;
    const float4 v = *(const float4*)((col < DIN) ? (s1 + col) : (s2 + col - DIN));
    wreg[k] = v.x; wreg[k+1] = v.y; wreg[k+2] = v.z; wreg[k+3] = v.w;
  }
}

template<int CPT>
DEV void dot16(const float* wreg, const float* inpP, float* dots){
  const int tid = threadIdx.x, p = tid & 15;
  const float* xi = inpP + p * (CPT + 4);
  float acc = 0.f;
  #pragma unroll
  for (int k = 0; k < CPT; k += 4){
    const float4 xv = *(const float4*)(xi + k);
    acc = fmaf(wreg[k],   xv.x, acc);
    acc = fmaf(wreg[k+1], xv.y, acc);
    acc = fmaf(wreg[k+2], xv.z, acc);
    acc = fmaf(wreg[k+3], xv.w, acc);
  }
  #pragma unroll
  for (int s = 1; s < 16; s <<= 1) acc += __shfl_xor(acc, s, 64);
  if (p == 0) dots[tid >> 4] = acc;
}

DEV void dot16_w1(const float* w1s, const float* inpP, float* dots){
  const int tid = threadIdx.x, p = tid & 15;
  const float* xi = inpP + p * 100;
  float acc = 0.f;
  #pragma unroll
  for (int k = 0; k < 96; k += 4){
    const float4 w4 = *(const float4*)(w1s + (k >> 2) * 1024 + tid * 4);
    const float4 xv = *(const float4*)(xi + k);
    acc = fmaf(w4.x, xv.x, acc);
    acc = fmaf(w4.y, xv.y, acc);
    acc = fmaf(w4.z, xv.z, acc);
    acc = fmaf(w4.w, xv.w, acc);
  }
  #pragma unroll
  for (int s = 1; s < 16; s <<= 1) acc += __shfl_xor(acc, s, 64);
  if (p == 0) dots[tid >> 4] = acc;
}

// ---------------- phase barrier (used twice, encoder only) ----------------
DEV void gbar_phase(u32* g, u32 ev){
  __syncthreads();
  if (threadIdx.x == 0){
    __hip_atomic_fetch_add(g, 1u, __ATOMIC_RELEASE, __HIP_MEMORY_SCOPE_AGENT);
    const u32 tgt = 256u * ev;
    while (ldA32(g) < tgt) __builtin_amdgcn_s_sleep(8);
    (void)__hip_atomic_fetch_add(g, 0u, __ATOMIC_ACQUIRE, __HIP_MEMORY_SCOPE_AGENT);
    asm volatile("" ::: "memory");
  }
  __syncthreads();
}

// ---------------- encoder layer (R7 verbatim) ----------------
template<int DIN, bool WRITE_XS>
DEV void enc_layer(const float* __restrict__ xg, float* __restrict__ xs_out,
                   const float* __restrict__ Wih, const float* __restrict__ Whh,
                   const float* __restrict__ bias,
                   u64* __restrict__ ht, float* __restrict__ hfinL, float* __restrict__ cfinL,
                   const int dir, const int jb4, SM& sm)
{
  constexpr int CPT = (DIN + 512) / 16;
  constexpr int NX  = DIN / 256;
  const int tid = threadIdx.x;
  float wreg[CPT];
  loadw<CPT, DIN>(wreg, Wih + (size_t)dir * 2048 * DIN, Whh + (size_t)dir * 2048 * 512, jb4);
  float b_i = 0.f, b_f = 0.f, b_g = 0.f, b_o = 0.f;
  if (tid < 4){
    const int j = jb4 + tid;
    sm.cst0[tid] = 0.f;
    b_i = bias[dir*2048 +        j];
    b_f = bias[dir*2048 +  512 + j];
    b_g = bias[dir*2048 + 1024 + j];
    b_o = bias[dir*2048 + 1536 + j];
  }
  float xr[NX];
  {
    const int t0 = dir ? 1023 : 0;
    #pragma unroll
    for (int i = 0; i < NX; ++i){
      const int c = tid + 256 * i;
      xr[i] = (DIN == 512) ? xg[(size_t)t0 * DIN + c] : ldAf(xg + (size_t)t0 * DIN + c);
    }
  }
  for (int step = 0; step < 1024; ++step){
    #pragma unroll
    for (int i = 0; i < NX; ++i) sm.inpP[pidx<CPT>(tid + 256 * i)] = xr[i];
    {
      const u64* hp = ht + (step & 1) * 512;
      const u32 want = (u32)step;
      u64 a = ldA64(hp + tid*2), b = ldA64(hp + tid*2 + 1);
      while ((u32)a != want){ __builtin_amdgcn_s_sleep(1); a = ldA64(hp + tid*2); }
      while ((u32)b != want){ __builtin_amdgcn_s_sleep(1); b = ldA64(hp + tid*2 + 1); }
      sm.inpP[pidx<CPT>(DIN + tid*2)]     = unpackH(a);
      sm.inpP[pidx<CPT>(DIN + tid*2 + 1)] = unpackH(b);
    }
    __syncthreads();
    if (step < 1023){
      const int tn = dir ? (1022 - step) : (step + 1);
      #pragma unroll
      for (int i = 0; i < NX; ++i){
        const int c = tid + 256 * i;
        xr[i] = (DIN == 512) ? xg[(size_t)tn * DIN + c] : ldAf(xg + (size_t)tn * DIN + c);
      }
    }
    dot16<CPT>(wreg, sm.inpP, sm.dots);
    __syncthreads();
    if (tid < 4){
      const float gi = sm.dots[tid]      + b_i;
      const float gf = sm.dots[4 + tid]  + b_f;
      const float gg = sm.dots[8 + tid]  + b_g;
      const float go = sm.dots[12 + tid] + b_o;
      const float cc = sigf(gf) * sm.cst0[tid] + sigf(gi) * tanhf(gg);
      const float hh = sigf(go) * tanhf(cc);
      sm.cst0[tid] = cc;
      const int t = dir ? (1023 - step) : step;
      const int j = jb4 + tid;
      stA64(ht + ((step + 1) & 1) * 512 + j, packHV(hh, (u32)(step + 1)));
      if (WRITE_XS) stAf(xs_out + (size_t)t * 1024 + dir * 512 + j, hh);
      if (step == 1023){ stAf(hfinL + dir*512 + j, hh); stAf(cfinL + dir*512 + j, cc); }
    }
    __syncthreads();
  }
}

// ---------------- init ----------------
__global__ void bilstm_init(u32* ws){
  for (u32 i = threadIdx.x; i < 32768u; i += 256u) ws[i] = 0u;
}

// ---------------- lin_W f32 -> fp16 + per-row max|w| ----------------
__global__ void cvt_lin(const float* __restrict__ w, uint4* __restrict__ o,
                        float* __restrict__ maxw, const int C){
  const int wv = threadIdx.x >> 6, lane = threadIdx.x & 63;
  const int stride = gridDim.x * 4;
  for (int r = blockIdx.x * 4 + wv; r < C; r += stride){
    const float4* src = (const float4*)(w + (size_t)r * 1024) + lane * 4;
    const float4 v0 = src[0], v1 = src[1], v2 = src[2], v3 = src[3];
    uint4 p0, p1;
    __half2 h;
    h = __floats2half2_rn(v0.x, v0.y); p0.x = *(const u32*)&h;
    h = __floats2half2_rn(v0.z, v0.w); p0.y = *(const u32*)&h;
    h = __floats2half2_rn(v1.x, v1.y); p0.z = *(const u32*)&h;
    h = __floats2half2_rn(v1.z, v1.w); p0.w = *(const u32*)&h;
    h = __floats2half2_rn(v2.x, v2.y); p1.x = *(const u32*)&h;
    h = __floats2half2_rn(v2.z, v2.w); p1.y = *(const u32*)&h;
    h = __floats2half2_rn(v3.x, v3.y); p1.z = *(const u32*)&h;
    h = __floats2half2_rn(v3.z, v3.w); p1.w = *(const u32*)&h;
    uint4* dst = o + (size_t)r * 128 + lane * 2;
    dst[0] = p0; dst[1] = p1;
    float m = fmaxf(fmaxf(fmaxf(fabsf(v0.x), fabsf(v0.y)), fmaxf(fabsf(v0.z), fabsf(v0.w))),
                    fmaxf(fmaxf(fabsf(v1.x), fabsf(v1.y)), fmaxf(fabsf(v1.z), fabsf(v1.w))));
    m = fmaxf(m, fmaxf(fmaxf(fabsf(v2.x), fabsf(v2.y)), fmaxf(fabsf(v2.z), fabsf(v2.w))));
    m = fmaxf(m, fmaxf(fmaxf(fabsf(v3.x), fabsf(v3.y)), fmaxf(fabsf(v3.z), fabsf(v3.w))));
    #pragma unroll
    for (int s = 1; s < 64; s <<= 1) m = fmaxf(m, __shfl_xor(m, s, 64));
    if (lane == 0) maxw[r] = m;
  }
}

// ---------------- persistent kernel ----------------
template<int LINFP16>
__global__ __launch_bounds__(256, 1)
void bilstm_persist(const float* __restrict__ x,
                    const float* __restrict__ eW0, const float* __restrict__ eU0, const float* __restrict__ eb0,
                    const float* __restrict__ eW1, const float* __restrict__ eU1, const float* __restrict__ eb1,
                    const float* __restrict__ dW0, const float* __restrict__ dU0, const float* __restrict__ db0,
                    const float* __restrict__ dW1, const float* __restrict__ dU1, const float* __restrict__ db1,
                    const float* __restrict__ linW, const float* __restrict__ linb,
                    const float* __restrict__ emb, const float* __restrict__ bos,
                    float* __restrict__ out, float* __restrict__ ws, const int L, const int C)
{
  __shared__ SM sm;
  const int w = blockIdx.x;
  const int tid = threadIdx.x;
  const int dir = (w >> 2) & 1;                    // dir confined to 4 XCDs
  const int jb4 = ((w >> 3) * 4 + (w & 3)) * 4;

  u64*  htagE = (u64*)ws;                          // [0,32768)
  u64*  h0t   = htagE + 4096;                      // [32768,49152)
  u64*  h1t   = h0t + 2048;                        // [49152,65536)
  float* hfin = (float*)(h1t + 2048);              // [65536,73728)
  float* cfin = hfin + 2048;                       // [73728,81920)
  u32*  gbar  = (u32*)(cfin + 2048);               // [81920,81924)
  u64*  gkey  = (u64*)((char*)ws + 98304);         // [98304,131072): 256 x 128B slots
  const u16*  linH = (const u16*)((const char*)ws + 131072);
  const float* maxw = (const float*)((const char*)ws + 131072 + (size_t)C * 2048);
  float* xs1  = out;                               // scratch; decoder rewrites all of out

  // ================= encoder =================
  enc_layer<512,  true >(x,   xs1,     eW0, eU0, eb0, htagE + (0*2 + dir)*1024, hfin,        cfin,        dir, jb4, sm);
  gbar_phase(gbar, 1);
  enc_layer<1024, false>(xs1, nullptr, eW1, eU1, eb1, htagE + (1*2 + dir)*1024, hfin + 1024, cfin + 1024, dir, jb4, sm);
  gbar_phase(gbar, 2);

  // ================= decoder =================
  float w0reg[64];
  loadw<64, 512>(w0reg, dW0 + (size_t)dir*2048*512, dU0 + (size_t)dir*2048*512, jb4);
  { // stage layer-1 weights into LDS SoA
    const int r = tid >> 4, p = tid & 15;
    const int R = 512 * (r >> 2) + jb4 + (r & 3);
    const float* s1 = dW1 + (size_t)dir*2048*1024 + (size_t)R * 1024;
    const float* s2 = dU1 + (size_t)dir*2048*512  + (size_t)R * 512;
    #pragma unroll
    for (int k = 0; k < 96; k += 4){
      const int col = p * 96 + k;
      const float4 v = *(const float4*)((col < 1024) ? (s1 + col) : (s2 + col - 1024));
      *(float4*)(sm.w1s + (k >> 2) * 1024 + tid * 4) = v;
    }
  }

  float b0i=0,b0f=0,b0g=0,b0o=0, b1i=0,b1f=0,b1g=0,b1o=0;
  if (tid < 4){
    const int j = jb4 + tid;
    sm.cst0[tid] = ldAf(&cfin[dir*512 + j]);
    sm.cst1[tid] = ldAf(&cfin[1024 + dir*512 + j]);
    b0i = db0[dir*2048 + j];        b0f = db0[dir*2048 + 512 + j];
    b0g = db0[dir*2048 + 1024 + j]; b0o = db0[dir*2048 + 1536 + j];
    b1i = db1[dir*2048 + j];        b1f = db1[dir*2048 + 512 + j];
    b1g = db1[dir*2048 + 1024 + j]; b1o = db1[dir*2048 + 1536 + j];
  }
  const int rbase = w * 196 + (w < 81 ? w : 81);
  const int rn    = 196 + (w < 81 ? 1 : 0);
  int tok = 0;

  for (int t = 0; t < L; ++t){
    const u32 tag = (u32)(t + 1);
    // ---- layer 0 (h-half from h0c LDS cache for t>0; global poll eliminated) ----
    {
      const float* src = (t == 0) ? bos : (emb + (size_t)tok * 512);
      sm.inpP[pidx<64>(tid)]       = src[tid];
      sm.inpP[pidx<64>(tid + 256)] = src[tid + 256];
      if (t == 0){
        sm.inpP[pidx<64>(512 + tid*2)]     = ldAf(&hfin[dir*512 + tid*2]);
        sm.inpP[pidx<64>(512 + tid*2 + 1)] = ldAf(&hfin[dir*512 + tid*2 + 1]);
      } else {
        // h0(t-1) cached in LDS during L1's poll at step t-1 (bit-identical payloads)
        sm.inpP[pidx<64>(512 + tid*2)]     = sm.h0c[dir*512 + tid*2];
        sm.inpP[pidx<64>(512 + tid*2 + 1)] = sm.h0c[dir*512 + tid*2 + 1];
      }
      __syncthreads();
      dot16<64>(w0reg, sm.inpP, sm.dots);
      __syncthreads();
      if (tid < 4){
        const float gi = sm.dots[tid] + b0i, gf = sm.dots[4+tid] + b0f;
        const float gg = sm.dots[8+tid] + b0g, go = sm.dots[12+tid] + b0o;
        const float cc = sigf(gf) * sm.cst0[tid] + sigf(gi) * tanhf(gg);
        const float hh = sigf(go) * tanhf(cc);
        sm.cst0[tid] = cc;
        stA64(h0t + (dir*2 + (t & 1))*512 + jb4 + tid, packHV(hh, tag));
      }
      __syncthreads();
    }

    // ---- layer 1 (polls h0(t) globally — required cross-WG gather; fills h0c.
    //      h1(t-1) comes from linp LDS cache; that poll is eliminated) ----
    {
      #pragma unroll
      for (int i = 0; i < 4; ++i){
        const int c = tid + 256 * i;
        const int d = c >> 9, idx = c & 511;
        const u64* hp = h0t + (d*2 + (t & 1)) * 512 + idx;
        u64 v = ldA64(hp);
        while ((u32)v != tag){ __builtin_amdgcn_s_sleep(1); v = ldA64(hp); }
        const float hv = unpackH(v);
        sm.inpP[pidx<96>(c)] = hv;
        sm.h0c[c] = hv;                              // cache for L0(t+1)
      }
      if (t == 0){
        sm.inpP[pidx<96>(1024 + tid*2)]     = ldAf(&hfin[1024 + dir*512 + tid*2]);
        sm.inpP[pidx<96>(1024 + tid*2 + 1)] = ldAf(&hfin[1024 + dir*512 + tid*2 + 1]);
      } else {
        sm.inpP[pidx<96>(1024 + tid*2)]     = sm.linp[dir*512 + tid*2];
        sm.inpP[pidx<96>(1024 + tid*2 + 1)] = sm.linp[dir*512 + tid*2 + 1];
      }
      __syncthreads();
      dot16_w1(sm.w1s, sm.inpP, sm.dots);
      __syncthreads();
      if (tid < 4){
        const float gi = sm.dots[tid] + b1i, gf = sm.dots[4+tid] + b1f;
        const float gg = sm.dots[8+tid] + b1g, go = sm.dots[12+tid] + b1o;
        const float cc = sigf(gf) * sm.cst1[tid] + sigf(gi) * tanhf(gg);
        const float hh = sigf(go) * tanhf(cc);
        sm.cst1[tid] = cc;
        stA64(h1t + (dir*2 + (t & 1))*512 + jb4 + tid, packHV(hh, tag));
      }
    }

    // ---- linear + local argmax ----
    {
      float pabs = 0.f;
      #pragma unroll
      for (int i = 0; i < 4; ++i){
        const int c = tid + 256 * i;
        const int d = c >> 9, idx = c & 511;
        const u64* hp = h1t + (d*2 + (t & 1)) * 512 + idx;
        u64 v = ldA64(hp);
        while ((u32)v != tag){ __builtin_amdgcn_s_sleep(1); v = ldA64(hp); }
        const float hv = unpackH(v);
        sm.linp[c] = hv;                             // doubles as h1 cache for L1(t+1)
        pabs += fabsf(hv);
      }
      const int wv = tid >> 6, lane = tid & 63;
      if constexpr (LINFP16){
        #pragma unroll
        for (int s = 1; s < 64; s <<= 1) pabs += __shfl_xor(pabs, s, 64);
        if (lane == 0) sm.red[wv] = pabs;
      }
      __syncthreads();

      const float4* ip4 = (const float4*)(sm.linp + lane * 16);
      const float4 q0 = ip4[0], q1 = ip4[1], q2 = ip4[2], q3 = ip4[3];
      u64 kmax = 0;
      const int rmaxr = rbase + rn - 1;

      if constexpr (LINFP16){
        const float sumabs = sm.red[0] + sm.red[1] + sm.red[2] + sm.red[3];
        const float cErr = sumabs * 7.5e-4f;
        float lb = -1e30f;
        for (int i0 = wv; i0 < rn; i0 += 16){
          const int ia = i0;
          const int ib = (i0 + 4  > rn - 1) ? rn - 1 : i0 + 4;
          const int ic = (i0 + 8  > rn - 1) ? rn - 1 : i0 + 8;
          const int id = (i0 + 12 > rn - 1) ? rn - 1 : i0 + 12;
          const int ra = rbase + ia, rb = rbase + ib, rc = rbase + ic, rd = rbase + id;
          const uint4* pa = (const uint4*)(linH + (size_t)ra * 1024) + lane * 2;
          const uint4* pb = (const uint4*)(linH + (size_t)rb * 1024) + lane * 2;
          const uint4* pc = (const uint4*)(linH + (size_t)rc * 1024) + lane * 2;
          const uint4* pd = (const uint4*)(linH + (size_t)rd * 1024) + lane * 2;
          const uint4 A0 = pa[0], A1 = pa[1];
          const uint4 B0 = pb[0], B1 = pb[1];
          const uint4 C0 = pc[0], C1 = pc[1];
          const uint4 D0 = pd[0], D1 = pd[1];
          float sa = dot8h(A0, q0, q1) + dot8h(A1, q2, q3);
          float sb = dot8h(B0, q0, q1) + dot8h(B1, q2, q3);
          float sc = dot8h(C0, q0, q1) + dot8h(C1, q2, q3);
          float sd = dot8h(D0, q0, q1) + dot8h(D1, q2, q3);
          #pragma unroll
          for (int sh = 1; sh < 64; sh <<= 1){
            sa += __shfl_xor(sa, sh, 64);
            sb += __shfl_xor(sb, sh, 64);
            sc += __shfl_xor(sc, sh, 64);
            sd += __shfl_xor(sd, sh, 64);
          }
          if (lane == 0){
            sa += linb[ra]; sb += linb[rb]; sc += linb[rc]; sd += linb[rd];
            out[(size_t)t * C + ra] = sa;
            out[(size_t)t * C + rb] = sb;
            out[(size_t)t * C + rc] = sc;
            out[(size_t)t * C + rd] = sd;
            const float ea = maxw[ra] * cErr + 1e-4f;
            const float eb = maxw[rb] * cErr + 1e-4f;
            const float ec = maxw[rc] * cErr + 1e-4f;
            const float ed = maxw[rd] * cErr + 1e-4f;
            sm.srow[ia] = sa; sm.erow[ia] = ea;
            sm.srow[ib] = sb; sm.erow[ib] = eb;
            sm.srow[ic] = sc; sm.erow[ic] = ec;
            sm.srow[id] = sd; sm.erow[id] = ed;
            lb = fmaxf(lb, sa - ea); lb = fmaxf(lb, sb - eb);
            lb = fmaxf(lb, sc - ec); lb = fmaxf(lb, sd - ed);
          }
        }
        if (lane == 0) sm.red[4 + wv] = lb;
        __syncthreads();
        const float Lb = fmaxf(fmaxf(sm.red[4], sm.red[5]), fmaxf(sm.red[6], sm.red[7]));
        // exact f32 recheck of candidates (provably includes the WG's true argmax)
        for (int i = wv; i < rn; i += 4){
          if (sm.srow[i] + sm.erow[i] >= Lb){
            const int row = rbase + i;
            const float4* wp = (const float4*)(linW + (size_t)row * 1024) + lane * 4;
            float s = dotrow(wp[0], wp[1], wp[2], wp[3], q0, q1, q2, q3);
            #pragma unroll
            for (int sh2 = 1; sh2 < 64; sh2 <<= 1) s += __shfl_xor(s, sh2, 64);
            if (lane == 0){
              s += linb[row];
              const u64 k = packKeyT(s, (u32)row, tag);
              if (k > kmax) kmax = k;
            }
          }
        }
      } else {
        for (int i0 = wv; i0 < rn; i0 += 16){
          const int ra = rbase + i0;
          const int rb = (ra + 4  > rmaxr) ? rmaxr : ra + 4;
          const int rc = (ra + 8  > rmaxr) ? rmaxr : ra + 8;
          const int rd = (ra + 12 > rmaxr) ? rmaxr : ra + 12;
          const float ba = linb[ra], bb = linb[rb], bc = linb[rc], bd = linb[rd];
          const float4* pa = (const float4*)(linW + (size_t)ra * 1024) + lane * 4;
          const float4* pb = (const float4*)(linW + (size_t)rb * 1024) + lane * 4;
          const float4* pc = (const float4*)(linW + (size_t)rc * 1024) + lane * 4;
          const float4* pd = (const float4*)(linW + (size_t)rd * 1024) + lane * 4;
          const float4 a0 = pa[0], a1 = pa[1], a2 = pa[2], a3 = pa[3];
          const float4 e0 = pb[0], e1 = pb[1], e2 = pb[2], e3 = pb[3];
          const float4 c0 = pc[0], c1 = pc[1], c2 = pc[2], c3 = pc[3];
          const float4 d0 = pd[0], d1 = pd[1], d2 = pd[2], d3 = pd[3];
          float sa = dotrow(a0,a1,a2,a3, q0,q1,q2,q3);
          float sb = dotrow(e0,e1,e2,e3, q0,q1,q2,q3);
          float sc = dotrow(c0,c1,c2,c3, q0,q1,q2,q3);
          float sd = dotrow(d0,d1,d2,d3, q0,q1,q2,q3);
          #pragma unroll
          for (int sh = 1; sh < 64; sh <<= 1){
            sa += __shfl_xor(sa, sh, 64);
            sb += __shfl_xor(sb, sh, 64);
            sc += __shfl_xor(sc, sh, 64);
            sd += __shfl_xor(sd, sh, 64);
          }
          if (lane == 0){
            sa += ba; sb += bb; sc += bc; sd += bd;
            out[(size_t)t * C + ra] = sa;
            out[(size_t)t * C + rb] = sb;
            out[(size_t)t * C + rc] = sc;
            out[(size_t)t * C + rd] = sd;
            u64 k;
            k = packKeyT(sa, (u32)ra, tag); if (k > kmax) kmax = k;
            k = packKeyT(sb, (u32)rb, tag); if (k > kmax) kmax = k;
            k = packKeyT(sc, (u32)rc, tag); if (k > kmax) kmax = k;
            k = packKeyT(sd, (u32)rd, tag); if (k > kmax) kmax = k;
          }
        }
      }
      if (lane == 0) sm.wkey[wv] = kmax;
    }

    // ---- distributed argmax exchange (R7 verbatim) ----
    __syncthreads();
    if (tid == 0){
      u64 k4 = sm.wkey[0];
      if (sm.wkey[1] > k4) k4 = sm.wkey[1];
      if (sm.wkey[2] > k4) k4 = sm.wkey[2];
      if (sm.wkey[3] > k4) k4 = sm.wkey[3];
      stA64(gkey + (size_t)w * 16, k4);              // own 128-B slot: no contention
    }
    __syncthreads();
    {
      const u64* p = gkey + (size_t)tid * 16;        // thread i polls WG i's slot
      u64 kv = ldA64(p);
      while ((u32)(kv & 0x7FFFu) != tag){ __builtin_amdgcn_s_sleep(1); kv = ldA64(p); }
      #pragma unroll
      for (int s = 1; s < 64; s <<= 1){
        const u64 o = (u64)__shfl_xor((unsigned long long)kv, s, 64);
        if (o > kv) kv = o;
      }
      if ((tid & 63) == 0) sm.wkey[tid >> 6] = kv;
    }
    __syncthreads();
    {
      u64 gk = sm.wkey[0];
      if (sm.wkey[1] > gk) gk = sm.wkey[1];
      if (sm.wkey[2] > gk) gk = sm.wkey[2];
      if (sm.wkey[3] > gk) gk = sm.wkey[3];
      tok = (int)(0x1FFFFu - ((u32)(gk >> 15) & 0x1FFFFu));
      if (w == 0 && tid == 0) out[(size_t)L * C + t] = (float)tok;
    }
  }
}

// ---------------- launch ----------------
extern "C" void kernel_launch(void* const* d_in, const int* in_sizes, int n_in,
                              void* d_out, int out_size, void* d_ws, size_t ws_size,
                              hipStream_t stream)
{
  const float* x    = (const float*)d_in[0];
  const float* eW0  = (const float*)d_in[1];
  const float* eU0  = (const float*)d_in[2];
  const float* eb0  = (const float*)d_in[3];
  const float* eW1  = (const float*)d_in[4];
  const float* eU1  = (const float*)d_in[5];
  const float* eb1  = (const float*)d_in[6];
  const float* dW0  = (const float*)d_in[7];
  const float* dU0  = (const float*)d_in[8];
  const float* db0  = (const float*)d_in[9];
  const float* dW1  = (const float*)d_in[10];
  const float* dU1  = (const float*)d_in[11];
  const float* db1  = (const float*)d_in[12];
  const float* linW = (const float*)d_in[13];
  const float* linb = (const float*)d_in[14];
  const float* emb  = (const float*)d_in[15];
  const float* bos  = (const float*)d_in[16];

  const int C = in_sizes[14];            // 50257
  const int L = out_size / (C + 1);      // 150
  const int nlin = in_sizes[13];         // C*1024

  const size_t need = 131072 + (size_t)nlin * 2 + (size_t)C * 4;
  const bool fp16lin = (ws_size >= need);

  hipLaunchKernelGGL(bilstm_init, dim3(1), dim3(256), 0, stream, (u32*)d_ws);
  if (fp16lin){
    hipLaunchKernelGGL(cvt_lin, dim3(2048), dim3(256), 0, stream,
                       linW, (uint4*)((char*)d_ws + 131072),
                       (float*)((char*)d_ws + 131072 + (size_t)C * 2048), C);
    hipLaunchKernelGGL((bilstm_persist<1>), dim3(256), dim3(256), 0, stream,
                       x, eW0, eU0, eb0, eW1, eU1, eb1,
                       dW0, dU0, db0, dW1, dU1, db1,
                       linW, linb, emb, bos,
                       (float*)d_out, (float*)d_ws, L, C);
  } else {
    hipLaunchKernelGGL((bilstm_persist<0>), dim3(256), dim3(256), 0, stream,
                       x, eW0, eU0, eb0, eW1, eU1, eb1,
                       dW0, dU0, db0, dW1, dU1, db1,
                       linW, linb, emb, bos,
                       (float*)d_out, (float*)d_ws, L, C);
  }
}